// Round 2
// baseline (246.613 us; speedup 1.0000x reference)
//
#include <hip/hip_runtime.h>
#include <hip/hip_bf16.h>

#define BB 8
#define NN 2048
#define FIN 128
#define FO 64
#define ALPHA 0.2f

typedef __attribute__((ext_vector_type(8))) short bf16x8;
typedef __attribute__((ext_vector_type(4))) float f32x4;
typedef __attribute__((ext_vector_type(4))) int i32x4;

typedef __attribute__((address_space(1))) const void gvoid;
typedef __attribute__((address_space(3))) void lvoid;

__device__ inline void gl_lds16(const void* g, void* l) {
    // async global->LDS, 16B per lane; LDS dest = uniform base + lane*16
    __builtin_amdgcn_global_load_lds((gvoid*)g, (lvoid*)l, 16, 0, 0);
}

__device__ inline short f2bf(float x) {
    unsigned u = __float_as_uint(x);
    u += 0x7fffu + ((u >> 16) & 1u);   // RNE, sign-agnostic, no NaN inputs here
    return (short)(u >> 16);
}

// monotone float <-> uint order map (for atomicMax on float values)
__device__ inline unsigned f2ord(float f) {
    unsigned u = __float_as_uint(f);
    return (u & 0x80000000u) ? ~u : (u | 0x80000000u);
}
__device__ inline float ord2f(unsigned v) {
    return __uint_as_float((v & 0x80000000u) ? (v & 0x7fffffffu) : ~v);
}

// ---------------- Kernel 0: init e2m (replaces hipMemsetAsync; graph-safe) ---
__global__ void init_kernel(unsigned* __restrict__ e2m) {
    if (threadIdx.x < BB) e2m[threadIdx.x] = 0u;   // 0 = below all ord-mapped floats
}

// ---------------- Kernel A: Wh = h@W; whF in MFMA B-fragment layout ----------
// whF[b][jc][ot][lane][8] shorts: lane L holds Wh[b][j=jc*32+(L>>4)*8+jj][o=ot*16+(L&15)]
// h rows are wave-uniform -> scalar (K$) loads; no LDS, no barrier.
// e2max folded in via ordered-uint atomicMax (one fewer big kernel launch).
__global__ __launch_bounds__(256) void wh_kernel(
    const float* __restrict__ h, const float* __restrict__ W,
    const float* __restrict__ a, float* __restrict__ e1, float* __restrict__ e2,
    unsigned* __restrict__ e2m, short* __restrict__ whF)
{
    const int t  = threadIdx.x;
    const int o  = t & 63;
    const int wv = t >> 6;                     // rows wv*8 .. wv*8+7
    const int r0 = blockIdx.x * 32;            // 32 rows per block (same batch)
    // wave-uniform row base -> uniform addresses -> s_load path
    const float* __restrict__ hrow =
        h + (size_t)(r0 + __builtin_amdgcn_readfirstlane(wv) * 8) * FIN;

    float acc[8];
#pragma unroll
    for (int rr = 0; rr < 8; rr++) acc[rr] = 0.f;

    for (int f = 0; f < FIN; f += 4) {
        const float w0 = W[(f + 0) * FO + o];
        const float w1 = W[(f + 1) * FO + o];
        const float w2 = W[(f + 2) * FO + o];
        const float w3 = W[(f + 3) * FO + o];
#pragma unroll
        for (int rr = 0; rr < 8; rr++) {
            const float4 hv = *(const float4*)(hrow + rr * FIN + f);  // uniform -> SGPR
            acc[rr] = fmaf(hv.x, w0, acc[rr]);
            acc[rr] = fmaf(hv.y, w1, acc[rr]);
            acc[rr] = fmaf(hv.z, w2, acc[rr]);
            acc[rr] = fmaf(hv.w, w3, acc[rr]);
        }
    }

    // fragment-layout store: one contiguous 16B per lane
    const int b   = r0 / NN;
    const int ib0 = r0 - b * NN;
    const int ibb = ib0 + wv * 8;              // first row this wave owns (mult of 8)
    const int jc  = ibb >> 5;
    const int qq  = (ibb >> 3) & 3;
    const int ot  = o >> 4, mm = o & 15;
    const int L   = mm + qq * 16;
    bf16x8 frag;
#pragma unroll
    for (int rr = 0; rr < 8; rr++) frag[rr] = f2bf(acc[rr]);
    *(bf16x8*)(whF + ((((size_t)(b * 64 + jc) * 4 + ot) * 64 + L) * 8)) = frag;

    const float a1 = a[o], a2 = a[FO + o];
    float vmax = -3.0e38f;
#pragma unroll
    for (int rr = 0; rr < 8; rr++) {
        float v1 = acc[rr] * a1, v2 = acc[rr] * a2;
#pragma unroll
        for (int msk = 32; msk >= 1; msk >>= 1) {
            v1 += __shfl_xor(v1, msk, 64);
            v2 += __shfl_xor(v2, msk, 64);
        }
        vmax = fmaxf(vmax, v2);                // all lanes hold the full sum
        if (o == 0) { e1[r0 + wv * 8 + rr] = v1; e2[r0 + wv * 8 + rr] = v2; }
    }
    if (o == 0) atomicMax(&e2m[b], f2ord(vmax));
}

// ---------------- Kernel B: fused attention, double-buffered adj pipeline ----
// block = (b, 16-row i-tile); 4 waves split j.
// Per tile t: [whF+e2 loads] [stage(t+1) gl_lds] [vmcnt(16) - counted, never 0]
//             [s_barrier] [compute] [lgkmcnt(0)] [s_barrier].  Loads stay in
// flight across barriers (T3/T4-lite); vmcnt(16) = 8 whF + 4 e2 + 4 next-stage
// ops issued after stage(t), so it guarantees stage(t) retired (in-order vmcnt)
// while the prefetch keeps flying.  e2 is L1-resident -> broadcast global loads.
struct SMemS { int adj[2][16][260]; };                 // dbuf; gl_lds writes 256 ints/row, stride 260
struct SMemC { float comb[4][16][64]; float lsum[4][16]; };
union __align__(16) SMemU { SMemS s; SMemC c; };       // 33280 B -> 4 blocks/CU

__global__ __launch_bounds__(256, 4) void attn_kernel(
    const int* __restrict__ adj, const float* __restrict__ e1,
    const float* __restrict__ e2, const unsigned* __restrict__ e2m,
    const short* __restrict__ whF, float* __restrict__ out)
{
    __shared__ SMemU sm;
    const int t = threadIdx.x, w = t >> 6, lane = t & 63;
    const int m = lane & 15, q = lane >> 4;
    const int blk = blockIdx.x;
    const int b  = blk >> 7;
    const int i0 = (blk & 127) * 16;
    const int i  = i0 + m;

    const float e2mx = ord2f(e2m[b]);
    const float e1v = e1[b * NN + i];
    float mi = e1v + e2mx;
    mi = mi > 0.f ? mi : ALPHA * mi;           // safe per-row max bound (leakyrelu monotone)

    const short* whFb = whF + (size_t)b * (64 * 4 * 64 * 8);
    const int* arow0 = adj + ((size_t)(b * NN + i0)) * NN + lane * 4;  // lane's 16B of a row
    const float* e2b = e2 + b * NN;

    f32x4 acc0 = {0.f,0.f,0.f,0.f}, acc1 = acc0, acc2 = acc0, acc3 = acc0;
    float lsum = 0.f;

    // prologue: stage tile 0 -> buf 0 (4 gl_lds per wave)
#pragma unroll
    for (int k = 0; k < 4; k++)
        gl_lds16(arow0 + (size_t)(w * 4 + k) * NN, &sm.s.adj[0][w * 4 + k][0]);

#pragma unroll 2
    for (int tt = 0; tt < 8; tt++) {
        const int j0 = tt * 256;
        const int cb = tt & 1;

        // --- pre-barrier loads: issued BEFORE stage(t+1) so consuming them
        //     never drains the prefetch (in-order vmcnt retirement) ---
        const short* bfpA = whFb + (size_t)((j0 + w * 64) >> 5) * 2048 + lane * 8;
        bf16x8 b00 = *(const bf16x8*)(bfpA);
        bf16x8 b01 = *(const bf16x8*)(bfpA + 512);
        bf16x8 b02 = *(const bf16x8*)(bfpA + 1024);
        bf16x8 b03 = *(const bf16x8*)(bfpA + 1536);
        const short* bfpB = bfpA + 2048;       // next 32-col slab (s2=1)
        bf16x8 b10 = *(const bf16x8*)(bfpB);
        bf16x8 b11 = *(const bf16x8*)(bfpB + 512);
        bf16x8 b12 = *(const bf16x8*)(bfpB + 1024);
        bf16x8 b13 = *(const bf16x8*)(bfpB + 1536);

        const float* e2w = e2b + j0 + w * 64 + q * 8;   // broadcast, L1-resident
        f32x4 ev00 = *(const f32x4*)(e2w);
        f32x4 ev01 = *(const f32x4*)(e2w + 4);
        f32x4 ev10 = *(const f32x4*)(e2w + 32);
        f32x4 ev11 = *(const f32x4*)(e2w + 36);

        asm volatile("" ::: "memory");         // keep the 12 loads above before stage issue

        if (tt < 7) {
            const int jn = j0 + 256;
#pragma unroll
            for (int k = 0; k < 4; k++)
                gl_lds16(arow0 + (size_t)(w * 4 + k) * NN + jn,
                         &sm.s.adj[cb ^ 1][w * 4 + k][0]);
            // 16 ops issued after stage(tt): 8 whF + 4 e2 + 4 stage(tt+1)
            asm volatile("s_waitcnt vmcnt(16)" ::: "memory");
        } else {
            // last tile: 12 ops issued after stage(7)
            asm volatile("s_waitcnt vmcnt(12)" ::: "memory");
        }
        __builtin_amdgcn_s_barrier();          // all waves' stage(tt) landed

#pragma unroll
        for (int s2 = 0; s2 < 2; s2++) {
            const int col = w * 64 + s2 * 32 + q * 8;
            i32x4 a0 = *(const i32x4*)&sm.s.adj[cb][m][col];
            i32x4 a1 = *(const i32x4*)&sm.s.adj[cb][m][col + 4];
            const f32x4 ev0 = s2 ? ev10 : ev00;
            const f32x4 ev1 = s2 ? ev11 : ev01;

            bf16x8 af;
#pragma unroll
            for (int jj = 0; jj < 8; jj++) {
                const int   av  = (jj < 4) ? a0[jj]  : a1[jj - 4];
                const float e2j = (jj < 4) ? ev0[jj] : ev1[jj - 4];
                float e = e1v + e2j;
                e = e > 0.f ? e : ALPHA * e;
                const float pe = (av > 0) ? __expf(e - mi) : 0.f;
                lsum += pe;
                af[jj] = f2bf(pe);
            }

            if (s2 == 0) {
                acc0 = __builtin_amdgcn_mfma_f32_16x16x32_bf16(af, b00, acc0, 0, 0, 0);
                acc1 = __builtin_amdgcn_mfma_f32_16x16x32_bf16(af, b01, acc1, 0, 0, 0);
                acc2 = __builtin_amdgcn_mfma_f32_16x16x32_bf16(af, b02, acc2, 0, 0, 0);
                acc3 = __builtin_amdgcn_mfma_f32_16x16x32_bf16(af, b03, acc3, 0, 0, 0);
            } else {
                acc0 = __builtin_amdgcn_mfma_f32_16x16x32_bf16(af, b10, acc0, 0, 0, 0);
                acc1 = __builtin_amdgcn_mfma_f32_16x16x32_bf16(af, b11, acc1, 0, 0, 0);
                acc2 = __builtin_amdgcn_mfma_f32_16x16x32_bf16(af, b12, acc2, 0, 0, 0);
                acc3 = __builtin_amdgcn_mfma_f32_16x16x32_bf16(af, b13, acc3, 0, 0, 0);
            }
        }
        // architecturally drain this wave's LDS reads of buf[cb] before any wave
        // can cross the barrier and issue stage(tt+2) into buf[cb]. lgkmcnt only
        // counts LDS/SMEM, so the global prefetch stays in flight.
        asm volatile("s_waitcnt lgkmcnt(0)" ::: "memory");
        __builtin_amdgcn_s_barrier();
    }

    // cross-wave combine in LDS (union reuse; loop's final barrier fences it)
    lsum += __shfl_xor(lsum, 16, 64);
    lsum += __shfl_xor(lsum, 32, 64);
    if (q == 0) sm.c.lsum[w][m] = lsum;
#pragma unroll
    for (int ot = 0; ot < 4; ot++) {
        f32x4 av = (ot == 0) ? acc0 : (ot == 1) ? acc1 : (ot == 2) ? acc2 : acc3;
#pragma unroll
        for (int reg = 0; reg < 4; reg++)
            sm.c.comb[w][q * 4 + reg][ot * 16 + m] = av[reg];
    }
    __syncthreads();

    const int row = t >> 4, c0 = (t & 15) * 4;
    f32x4 sum = *(const f32x4*)&sm.c.comb[0][row][c0];
#pragma unroll
    for (int ww = 1; ww < 4; ww++) {
        f32x4 sv = *(const f32x4*)&sm.c.comb[ww][row][c0];
        sum.x += sv.x; sum.y += sv.y; sum.z += sv.z; sum.w += sv.w;
    }
    float l = sm.c.lsum[0][row] + sm.c.lsum[1][row] + sm.c.lsum[2][row] + sm.c.lsum[3][row];
    l = fmaxf(l, 1e-30f);
    const float rl = 1.f / l;
    float vr[4] = { sum.x * rl, sum.y * rl, sum.z * rl, sum.w * rl };
    f32x4 res;
#pragma unroll
    for (int kk = 0; kk < 4; kk++)
        res[kk] = vr[kk] > 0.f ? vr[kk] : (__expf(vr[kk]) - 1.f);
    *(f32x4*)&out[((size_t)(b * NN + i0 + row)) * FO + c0] = res;
}

extern "C" void kernel_launch(void* const* d_in, const int* in_sizes, int n_in,
                              void* d_out, int out_size, void* d_ws, size_t ws_size,
                              hipStream_t stream) {
    const float* h   = (const float*)d_in[0];
    const int*   adj = (const int*)d_in[1];
    const float* W   = (const float*)d_in[2];
    const float* a   = (const float*)d_in[3];
    float* out = (float*)d_out;

    char* ws = (char*)d_ws;
    short* whF = (short*)ws;                                   // 2 MB
    size_t off = (size_t)BB * 64 * 4 * 64 * 8 * sizeof(short);
    float* e1  = (float*)(ws + off);  off += (size_t)BB * NN * 4;
    float* e2  = (float*)(ws + off);  off += (size_t)BB * NN * 4;
    unsigned* e2m = (unsigned*)(ws + off);

    init_kernel<<<1, 64, 0, stream>>>(e2m);
    wh_kernel<<<(BB * NN) / 32, 256, 0, stream>>>(h, W, a, e1, e2, e2m, whF);
    attn_kernel<<<BB * (NN / 16), 256, 0, stream>>>(adj, e1, e2, e2m, whF, out);
}

// Round 3
// 222.126 us; speedup vs baseline: 1.1102x; 1.1102x over previous
//
#include <hip/hip_runtime.h>
#include <hip/hip_bf16.h>

#define BB 8
#define NN 2048
#define FIN 128
#define FO 64
#define ALPHA 0.2f

typedef __attribute__((ext_vector_type(8))) short bf16x8;
typedef __attribute__((ext_vector_type(4))) float f32x4;
typedef __attribute__((ext_vector_type(4))) int i32x4;

typedef __attribute__((address_space(1))) const void gvoid;
typedef __attribute__((address_space(3))) void lvoid;

__device__ inline void gl_lds16(const void* g, void* l) {
    // async global->LDS, 16B per lane; LDS dest = uniform base + lane*16
    __builtin_amdgcn_global_load_lds((gvoid*)g, (lvoid*)l, 16, 0, 0);
}

__device__ inline short f2bf(float x) {
    unsigned u = __float_as_uint(x);
    u += 0x7fffu + ((u >> 16) & 1u);   // RNE, sign-agnostic, no NaN inputs here
    return (short)(u >> 16);
}

// ---------------- Kernel A: Wh = h@W; whF in MFMA B-fragment layout ----------
// whF[b][jc][ot][lane][8] shorts: lane L holds Wh[b][j=jc*32+(L>>4)*8+jj][o=ot*16+(L&15)]
// h rows are wave-uniform -> scalar (K$) loads; no LDS, no barrier.
// e2 block-maxes: ONE non-atomic float store per wave into e2p[b][0..255]
// (round-2's atomicMax on a single cacheline serialized ~8k RMWs — removed).
__global__ __launch_bounds__(256) void wh_kernel(
    const float* __restrict__ h, const float* __restrict__ W,
    const float* __restrict__ a, float* __restrict__ e1, float* __restrict__ e2,
    float* __restrict__ e2p, short* __restrict__ whF)
{
    const int t  = threadIdx.x;
    const int o  = t & 63;
    const int wv = t >> 6;                     // rows wv*8 .. wv*8+7
    const int r0 = blockIdx.x * 32;            // 32 rows per block (same batch)
    // wave-uniform row base -> uniform addresses -> s_load path
    const float* __restrict__ hrow =
        h + (size_t)(r0 + __builtin_amdgcn_readfirstlane(wv) * 8) * FIN;

    float acc[8];
#pragma unroll
    for (int rr = 0; rr < 8; rr++) acc[rr] = 0.f;

    for (int f = 0; f < FIN; f += 4) {
        const float w0 = W[(f + 0) * FO + o];
        const float w1 = W[(f + 1) * FO + o];
        const float w2 = W[(f + 2) * FO + o];
        const float w3 = W[(f + 3) * FO + o];
#pragma unroll
        for (int rr = 0; rr < 8; rr++) {
            const float4 hv = *(const float4*)(hrow + rr * FIN + f);  // uniform -> SGPR
            acc[rr] = fmaf(hv.x, w0, acc[rr]);
            acc[rr] = fmaf(hv.y, w1, acc[rr]);
            acc[rr] = fmaf(hv.z, w2, acc[rr]);
            acc[rr] = fmaf(hv.w, w3, acc[rr]);
        }
    }

    // fragment-layout store: one contiguous 16B per lane
    const int b   = r0 / NN;
    const int ib0 = r0 - b * NN;
    const int ibb = ib0 + wv * 8;              // first row this wave owns (mult of 8)
    const int jc  = ibb >> 5;
    const int qq  = (ibb >> 3) & 3;
    const int ot  = o >> 4, mm = o & 15;
    const int L   = mm + qq * 16;
    bf16x8 frag;
#pragma unroll
    for (int rr = 0; rr < 8; rr++) frag[rr] = f2bf(acc[rr]);
    *(bf16x8*)(whF + ((((size_t)(b * 64 + jc) * 4 + ot) * 64 + L) * 8)) = frag;

    const float a1 = a[o], a2 = a[FO + o];
    float vmax = -3.0e38f;
#pragma unroll
    for (int rr = 0; rr < 8; rr++) {
        float v1 = acc[rr] * a1, v2 = acc[rr] * a2;
#pragma unroll
        for (int msk = 32; msk >= 1; msk >>= 1) {
            v1 += __shfl_xor(v1, msk, 64);
            v2 += __shfl_xor(v2, msk, 64);
        }
        vmax = fmaxf(vmax, v2);                // all lanes hold the full sum
        if (o == 0) { e1[r0 + wv * 8 + rr] = v1; e2[r0 + wv * 8 + rr] = v2; }
    }
    // per-wave partial max, contention-free: e2p[b*256 + blockInBatch*4 + wv]
    if (o == 0) e2p[b * 256 + (ib0 >> 5) * 4 + wv] = vmax;
}

// ---------------- Kernel B: fused attention, double-buffered adj pipeline ----
// block = (b, 16-row i-tile); 4 waves split j.
// Block start: reduce e2p[b][0..255] -> batch e2max (one load/thread + shfl +
// tiny LDS reduce + __syncthreads; the implicit vmcnt(0) there drains only the
// two scalar loads — prologue staging is issued AFTER it).
// Per tile t: [whF+e2 loads] [stage(t+1) gl_lds] [vmcnt(16) - counted, never 0]
//             [s_barrier] [compute] [lgkmcnt(0)] [s_barrier].  Loads stay in
// flight across barriers (T3/T4-lite); vmcnt(16) = 8 whF + 4 e2 + 4 next-stage
// ops issued after stage(t), so it guarantees stage(t) retired (in-order vmcnt)
// while the prefetch keeps flying.  e2 is L1-resident -> broadcast global loads.
struct SMemS { int adj[2][16][260]; };                 // dbuf; gl_lds writes 256 ints/row, stride 260
struct SMemC { float comb[4][16][64]; float lsum[4][16]; };
union __align__(16) SMemU { SMemS s; SMemC c; };       // 33280 B -> 4 blocks/CU

__global__ __launch_bounds__(256, 4) void attn_kernel(
    const int* __restrict__ adj, const float* __restrict__ e1,
    const float* __restrict__ e2, const float* __restrict__ e2p,
    const short* __restrict__ whF, float* __restrict__ out)
{
    __shared__ SMemU sm;
    __shared__ float red4[4];
    const int t = threadIdx.x, w = t >> 6, lane = t & 63;
    const int m = lane & 15, q = lane >> 4;
    const int blk = blockIdx.x;
    const int b  = blk >> 7;
    const int i0 = (blk & 127) * 16;
    const int i  = i0 + m;

    // ---- batch e2max from per-wave partials (256 floats, L2-resident) ----
    float pv = e2p[b * 256 + t];
    const float e1v = e1[b * NN + i];
#pragma unroll
    for (int k = 32; k >= 1; k >>= 1) pv = fmaxf(pv, __shfl_xor(pv, k, 64));
    if (lane == 0) red4[w] = pv;
    __syncthreads();                            // drains only the 2 loads above
    const float e2mx = fmaxf(fmaxf(red4[0], red4[1]), fmaxf(red4[2], red4[3]));

    float mi = e1v + e2mx;
    mi = mi > 0.f ? mi : ALPHA * mi;           // safe per-row max bound (leakyrelu monotone)

    const short* whFb = whF + (size_t)b * (64 * 4 * 64 * 8);
    const int* arow0 = adj + ((size_t)(b * NN + i0)) * NN + lane * 4;  // lane's 16B of a row
    const float* e2b = e2 + b * NN;

    f32x4 acc0 = {0.f,0.f,0.f,0.f}, acc1 = acc0, acc2 = acc0, acc3 = acc0;
    float lsum = 0.f;

    // prologue: stage tile 0 -> buf 0 (4 gl_lds per wave); AFTER the syncthreads
#pragma unroll
    for (int k = 0; k < 4; k++)
        gl_lds16(arow0 + (size_t)(w * 4 + k) * NN, &sm.s.adj[0][w * 4 + k][0]);

#pragma unroll 2
    for (int tt = 0; tt < 8; tt++) {
        const int j0 = tt * 256;
        const int cb = tt & 1;

        // --- pre-barrier loads: issued BEFORE stage(t+1) so consuming them
        //     never drains the prefetch (in-order vmcnt retirement) ---
        const short* bfpA = whFb + (size_t)((j0 + w * 64) >> 5) * 2048 + lane * 8;
        bf16x8 b00 = *(const bf16x8*)(bfpA);
        bf16x8 b01 = *(const bf16x8*)(bfpA + 512);
        bf16x8 b02 = *(const bf16x8*)(bfpA + 1024);
        bf16x8 b03 = *(const bf16x8*)(bfpA + 1536);
        const short* bfpB = bfpA + 2048;       // next 32-col slab (s2=1)
        bf16x8 b10 = *(const bf16x8*)(bfpB);
        bf16x8 b11 = *(const bf16x8*)(bfpB + 512);
        bf16x8 b12 = *(const bf16x8*)(bfpB + 1024);
        bf16x8 b13 = *(const bf16x8*)(bfpB + 1536);

        const float* e2w = e2b + j0 + w * 64 + q * 8;   // broadcast, L1-resident
        f32x4 ev00 = *(const f32x4*)(e2w);
        f32x4 ev01 = *(const f32x4*)(e2w + 4);
        f32x4 ev10 = *(const f32x4*)(e2w + 32);
        f32x4 ev11 = *(const f32x4*)(e2w + 36);

        asm volatile("" ::: "memory");         // keep the 12 loads above before stage issue

        if (tt < 7) {
            const int jn = j0 + 256;
#pragma unroll
            for (int k = 0; k < 4; k++)
                gl_lds16(arow0 + (size_t)(w * 4 + k) * NN + jn,
                         &sm.s.adj[cb ^ 1][w * 4 + k][0]);
            // 16 ops issued after stage(tt): 8 whF + 4 e2 + 4 stage(tt+1)
            asm volatile("s_waitcnt vmcnt(16)" ::: "memory");
        } else {
            // last tile: 12 ops issued after stage(7)
            asm volatile("s_waitcnt vmcnt(12)" ::: "memory");
        }
        __builtin_amdgcn_s_barrier();          // all waves' stage(tt) landed

#pragma unroll
        for (int s2 = 0; s2 < 2; s2++) {
            const int col = w * 64 + s2 * 32 + q * 8;
            i32x4 a0 = *(const i32x4*)&sm.s.adj[cb][m][col];
            i32x4 a1 = *(const i32x4*)&sm.s.adj[cb][m][col + 4];
            const f32x4 ev0 = s2 ? ev10 : ev00;
            const f32x4 ev1 = s2 ? ev11 : ev01;

            bf16x8 af;
#pragma unroll
            for (int jj = 0; jj < 8; jj++) {
                const int   av  = (jj < 4) ? a0[jj]  : a1[jj - 4];
                const float e2j = (jj < 4) ? ev0[jj] : ev1[jj - 4];
                float e = e1v + e2j;
                e = e > 0.f ? e : ALPHA * e;
                const float pe = (av > 0) ? __expf(e - mi) : 0.f;
                lsum += pe;
                af[jj] = f2bf(pe);
            }

            if (s2 == 0) {
                acc0 = __builtin_amdgcn_mfma_f32_16x16x32_bf16(af, b00, acc0, 0, 0, 0);
                acc1 = __builtin_amdgcn_mfma_f32_16x16x32_bf16(af, b01, acc1, 0, 0, 0);
                acc2 = __builtin_amdgcn_mfma_f32_16x16x32_bf16(af, b02, acc2, 0, 0, 0);
                acc3 = __builtin_amdgcn_mfma_f32_16x16x32_bf16(af, b03, acc3, 0, 0, 0);
            } else {
                acc0 = __builtin_amdgcn_mfma_f32_16x16x32_bf16(af, b10, acc0, 0, 0, 0);
                acc1 = __builtin_amdgcn_mfma_f32_16x16x32_bf16(af, b11, acc1, 0, 0, 0);
                acc2 = __builtin_amdgcn_mfma_f32_16x16x32_bf16(af, b12, acc2, 0, 0, 0);
                acc3 = __builtin_amdgcn_mfma_f32_16x16x32_bf16(af, b13, acc3, 0, 0, 0);
            }
        }
        // architecturally drain this wave's LDS reads of buf[cb] before any wave
        // can cross the barrier and issue stage(tt+2) into buf[cb]. lgkmcnt only
        // counts LDS/SMEM, so the global prefetch stays in flight.
        asm volatile("s_waitcnt lgkmcnt(0)" ::: "memory");
        __builtin_amdgcn_s_barrier();
    }

    // cross-wave combine in LDS (union reuse; loop's final barrier fences it)
    lsum += __shfl_xor(lsum, 16, 64);
    lsum += __shfl_xor(lsum, 32, 64);
    if (q == 0) sm.c.lsum[w][m] = lsum;
#pragma unroll
    for (int ot = 0; ot < 4; ot++) {
        f32x4 av = (ot == 0) ? acc0 : (ot == 1) ? acc1 : (ot == 2) ? acc2 : acc3;
#pragma unroll
        for (int reg = 0; reg < 4; reg++)
            sm.c.comb[w][q * 4 + reg][ot * 16 + m] = av[reg];
    }
    __syncthreads();

    const int row = t >> 4, c0 = (t & 15) * 4;
    f32x4 sum = *(const f32x4*)&sm.c.comb[0][row][c0];
#pragma unroll
    for (int ww = 1; ww < 4; ww++) {
        f32x4 sv = *(const f32x4*)&sm.c.comb[ww][row][c0];
        sum.x += sv.x; sum.y += sv.y; sum.z += sv.z; sum.w += sv.w;
    }
    float l = sm.c.lsum[0][row] + sm.c.lsum[1][row] + sm.c.lsum[2][row] + sm.c.lsum[3][row];
    l = fmaxf(l, 1e-30f);
    const float rl = 1.f / l;
    float vr[4] = { sum.x * rl, sum.y * rl, sum.z * rl, sum.w * rl };
    f32x4 res;
#pragma unroll
    for (int kk = 0; kk < 4; kk++)
        res[kk] = vr[kk] > 0.f ? vr[kk] : (__expf(vr[kk]) - 1.f);
    *(f32x4*)&out[((size_t)(b * NN + i0 + row)) * FO + c0] = res;
}

extern "C" void kernel_launch(void* const* d_in, const int* in_sizes, int n_in,
                              void* d_out, int out_size, void* d_ws, size_t ws_size,
                              hipStream_t stream) {
    const float* h   = (const float*)d_in[0];
    const int*   adj = (const int*)d_in[1];
    const float* W   = (const float*)d_in[2];
    const float* a   = (const float*)d_in[3];
    float* out = (float*)d_out;

    char* ws = (char*)d_ws;
    short* whF = (short*)ws;                                   // 2 MB
    size_t off = (size_t)BB * 64 * 4 * 64 * 8 * sizeof(short);
    float* e1  = (float*)(ws + off);  off += (size_t)BB * NN * 4;
    float* e2  = (float*)(ws + off);  off += (size_t)BB * NN * 4;
    float* e2p = (float*)(ws + off);                           // 8 x 256 partial maxes

    wh_kernel<<<(BB * NN) / 32, 256, 0, stream>>>(h, W, a, e1, e2, e2p, whF);
    attn_kernel<<<BB * (NN / 16), 256, 0, stream>>>(adj, e1, e2, e2p, whF, out);
}